// Round 2
// baseline (96.728 us; speedup 1.0000x reference)
//
#include <hip/hip_runtime.h>

#define FEPS 1e-5f

constexpr int Bn = 4, Hn = 16, Sn = 4096, Dn = 64;
constexpr int NHEAD = Bn * Hn;          // 64 heads
constexpr int CHUNKS = 8;               // pass1 S-chunks per head -> 512 blocks = 2/CU
constexpr int CH_S = Sn / CHUNKS;       // 512 rows per pass1 block
constexpr int STG = 64;                 // rows per LDS stage
constexpr int SLOT = Dn * Dn + Dn;      // 4160 floats: kv then ksum

// direct global->LDS, 16B per lane (dest = wave-uniform base + lane*16)
__device__ __forceinline__ void gload16(const float* g, float* l) {
    __builtin_amdgcn_global_load_lds(
        (const __attribute__((address_space(1))) void*)g,
        (__attribute__((address_space(3))) void*)l,
        16, 0, 0);
}

// ---------------- Pass 1: partial kv = K^T V and k_sum over an S-chunk ----------------
// Each wave computes a FULL 64x64 kv partial (8x8 per lane) over its own s rows;
// 4 wave-partials reduced through LDS at the end; one slot written per block.
__global__ __launch_bounds__(256) void pass1(const float* __restrict__ K,
                                             const float* __restrict__ V,
                                             float* __restrict__ part,
                                             int ch_s) {
    __shared__ float lds[2][2][STG][Dn];   // [buf][K/V][row][d] : 64 KB
    __shared__ float ksred[4][Dn];         // 1 KB

    const int head = blockIdx.x;
    const int chunk = blockIdx.y;
    const int t = threadIdx.x;
    const int w = t >> 6;                  // wave 0..3
    const int l = t & 63;
    const int d0 = (l >> 3) * 8;           // kv row-tile base (K dim)
    const int e0 = (l & 7) * 8;            // kv col-tile base (V dim)
    const int nstg = ch_s / STG;

    const size_t base = ((size_t)head * Sn + (size_t)chunk * ch_s) * Dn;
    const float* Kg = K + base;
    const float* Vg = V + base;

    float acc[8][8] = {};
    float ks[8] = {};

    auto STAGE = [&](int s, int b) {
        const float* kg = Kg + (size_t)s * STG * Dn + t * 4;
        const float* vg = Vg + (size_t)s * STG * Dn + t * 4;
        float* kl = &lds[b][0][0][0] + w * 256;   // wave-uniform LDS base
        float* vl = &lds[b][1][0][0] + w * 256;
        #pragma unroll
        for (int i = 0; i < 4; ++i) {
            gload16(kg + i * 1024, kl + i * 1024);
            gload16(vg + i * 1024, vl + i * 1024);
        }
    };

    STAGE(0, 0);
    __syncthreads();   // drains vmcnt(0) before barrier (HIP __syncthreads semantics)

    for (int st = 0; st < nstg; ++st) {
        const int cur = st & 1;
        if (st + 1 < nstg) STAGE(st + 1, cur ^ 1);
        const float (*kb)[Dn] = lds[cur][0];
        const float (*vb)[Dn] = lds[cur][1];
        #pragma unroll
        for (int r = 0; r < 16; ++r) {
            const int s = w * 16 + r;      // this wave's rows of the stage
            float4 ka = *(const float4*)&kb[s][d0];
            float4 kc = *(const float4*)&kb[s][d0 + 4];
            float4 va = *(const float4*)&vb[s][e0];
            float4 vc = *(const float4*)&vb[s][e0 + 4];
            float kf[8] = {ka.x, ka.y, ka.z, ka.w, kc.x, kc.y, kc.z, kc.w};
            float vf[8] = {va.x, va.y, va.z, va.w, vc.x, vc.y, vc.z, vc.w};
            #pragma unroll
            for (int i = 0; i < 8; ++i) {
                ks[i] += kf[i];
                #pragma unroll
                for (int j = 0; j < 8; ++j) acc[i][j] += kf[i] * vf[j];
            }
        }
        __syncthreads();   // stage t+1 landed (vmcnt drain) + all waves done reading cur
    }

    // ---- block reduction of the 4 wave partials (lds[0] is free: last stage read lds[1]) ----
    float* redA = &lds[0][0][0][0];
    float* redB = &lds[0][1][0][0];
    if (w == 0 || w == 1) {
        float* dst = (w == 0) ? redA : redB;
        #pragma unroll
        for (int i = 0; i < 8; ++i) {
            *(float4*)&dst[(d0 + i) * Dn + e0] =
                make_float4(acc[i][0], acc[i][1], acc[i][2], acc[i][3]);
            *(float4*)&dst[(d0 + i) * Dn + e0 + 4] =
                make_float4(acc[i][4], acc[i][5], acc[i][6], acc[i][7]);
        }
    }
    if ((l & 7) == 0) {
        #pragma unroll
        for (int i = 0; i < 8; ++i) ksred[w][d0 + i] = ks[i];
    }
    __syncthreads();
    if (w == 2 || w == 3) {
        float* dst = (w == 2) ? redA : redB;
        #pragma unroll
        for (int i = 0; i < 8; ++i)
            #pragma unroll
            for (int j = 0; j < 8; ++j) dst[(d0 + i) * Dn + e0 + j] += acc[i][j];
    }
    __syncthreads();

    float* slot = part + ((size_t)chunk * NHEAD + head) * SLOT;
    #pragma unroll
    for (int q = 0; q < 4; ++q) {
        int f = q * 1024 + t * 4;          // coalesced across lanes
        float4 a = *(const float4*)&redA[f];
        float4 b = *(const float4*)&redB[f];
        *(float4*)&slot[f] = make_float4(a.x + b.x, a.y + b.y, a.z + b.z, a.w + b.w);
    }
    if (t < Dn)
        slot[Dn * Dn + t] = ksred[0][t] + ksred[1][t] + ksred[2][t] + ksred[3][t];
}

// ---------------- Reduce chunk-partials -> final slot layout [head][4096 kv + 64 ksum] ----------------
__global__ __launch_bounds__(256) void reduce_partials(const float* __restrict__ part,
                                                       float* __restrict__ slots) {
    const int head = blockIdx.x;
    const int idx = blockIdx.y * 256 + threadIdx.x;
    if (idx >= SLOT) return;
    float s = 0.f;
    #pragma unroll
    for (int c = 0; c < CHUNKS; ++c)
        s += part[((size_t)c * NHEAD + head) * SLOT + idx];
    slots[(size_t)head * SLOT + idx] = s;
}

// ---------------- Pass 2: out = (Q / (Q.ksum + eps)) @ kv ----------------
__global__ __launch_bounds__(256) void pass2(const float* __restrict__ Q,
                                             const float* __restrict__ slots,
                                             float* __restrict__ out) {
    const int head = blockIdx.x;
    const int rc = blockIdx.y;  // 64-row chunk
    const int t = threadIdx.x;
    const int ti = t >> 4, tj = t & 15;
    const int r0 = ti * 4, e0 = tj * 4;   // 4 rows x 4 cols per thread

    __shared__ float kvs[Dn][Dn];
    __shared__ float qT[Dn][68];          // transposed Q tile, padded
    __shared__ float kss[Dn];

    const float* kvh = slots + (size_t)head * SLOT;

    // stage kv (16KB; L2/L3-resident after reduce)
    const float4* kvsrc = (const float4*)kvh;
    float4* kvdst = (float4*)&kvs[0][0];
    #pragma unroll
    for (int kk = 0; kk < 4; ++kk) kvdst[t + 256 * kk] = kvsrc[t + 256 * kk];
    if (t < 16) ((float4*)kss)[t] = ((const float4*)(kvh + Dn * Dn))[t];

    // stage Q tile transposed: qT[d][row]
    const float4* Qsrc = (const float4*)(Q + ((size_t)head * Sn + (size_t)rc * 64) * Dn);
    #pragma unroll
    for (int kk = 0; kk < 4; ++kk) {
        int f = t + 256 * kk;
        int row = f >> 4, d4 = (f & 15) * 4;
        float4 q4 = Qsrc[f];
        qT[d4 + 0][row] = q4.x;
        qT[d4 + 1][row] = q4.y;
        qT[d4 + 2][row] = q4.z;
        qT[d4 + 3][row] = q4.w;
    }
    __syncthreads();

    float acc[4][4] = {};
    float dn[4] = {0.f, 0.f, 0.f, 0.f};
    #pragma unroll 8
    for (int d = 0; d < Dn; ++d) {
        float4 a = *(const float4*)&qT[d][r0];     // q for 4 rows at dim d
        float4 b = *(const float4*)&kvs[d][e0];    // kv row d, 4 cols
        float ksd = kss[d];
        float av[4] = {a.x, a.y, a.z, a.w};
        float bv[4] = {b.x, b.y, b.z, b.w};
        #pragma unroll
        for (int i = 0; i < 4; ++i) {
            dn[i] += av[i] * ksd;
            #pragma unroll
            for (int j = 0; j < 4; ++j) acc[i][j] += av[i] * bv[j];
        }
    }

    float* Oh = out + ((size_t)head * Sn + (size_t)rc * 64) * Dn;
    #pragma unroll
    for (int i = 0; i < 4; ++i) {
        float inv = 1.0f / (dn[i] + FEPS);
        float4 r;
        r.x = acc[i][0] * inv; r.y = acc[i][1] * inv;
        r.z = acc[i][2] * inv; r.w = acc[i][3] * inv;
        *(float4*)&Oh[(size_t)(r0 + i) * Dn + e0] = r;
    }
}

extern "C" void kernel_launch(void* const* d_in, const int* in_sizes, int n_in,
                              void* d_out, int out_size, void* d_ws, size_t ws_size,
                              hipStream_t stream) {
    (void)in_sizes; (void)n_in; (void)out_size;
    const float* Q = (const float*)d_in[0];
    const float* K = (const float*)d_in[1];
    const float* V = (const float*)d_in[2];
    float* out = (float*)d_out;

    float* slots = (float*)d_ws;                         // [64][4160] final kv+ksum
    float* part = slots + (size_t)NHEAD * SLOT;          // [CHUNKS][64][4160]
    const size_t need = (size_t)(1 + CHUNKS) * NHEAD * SLOT * sizeof(float);  // ~9.6 MB

    if (ws_size >= need) {
        hipLaunchKernelGGL(pass1, dim3(NHEAD, CHUNKS), dim3(256), 0, stream,
                           K, V, part, CH_S);
        hipLaunchKernelGGL(reduce_partials, dim3(NHEAD, (SLOT + 255) / 256), dim3(256), 0, stream,
                           part, slots);
    } else {
        // single-chunk fallback: one block per head writes the final slot directly
        hipLaunchKernelGGL(pass1, dim3(NHEAD, 1), dim3(256), 0, stream,
                           K, V, slots, Sn);
    }
    hipLaunchKernelGGL(pass2, dim3(NHEAD, Sn / 64), dim3(256), 0, stream,
                       Q, slots, out);
}

// Round 3
// 93.494 us; speedup vs baseline: 1.0346x; 1.0346x over previous
//
#include <hip/hip_runtime.h>

#define FEPS 1e-5f

constexpr int Bn = 4, Hn = 16, Sn = 4096, Dn = 64;
constexpr int NHEAD = Bn * Hn;          // 64 heads
constexpr int STG = 32;                 // rows per LDS stage
constexpr int SLOT = Dn * Dn + Dn;      // 4160 floats: kv then ksum

// direct global->LDS, 16B per lane (dest = wave-uniform base + lane*16)
__device__ __forceinline__ void gload16(const float* g, float* l) {
    __builtin_amdgcn_global_load_lds(
        (const __attribute__((address_space(1))) void*)g,
        (__attribute__((address_space(3))) void*)l,
        16, 0, 0);
}

// ---------------- Pass 1: partial kv = K^T V and k_sum over an S-chunk ----------------
// Each wave computes a FULL 64x64 kv partial (8x8 per lane) over its own rows;
// 4 wave-partials reduced through LDS at the end; one slot written per block.
// LDS kept at 33KB so 3 blocks/CU stay resident (VGPR-limited).
__global__ __launch_bounds__(256, 3) void pass1(const float* __restrict__ K,
                                                const float* __restrict__ V,
                                                float* __restrict__ part,
                                                int ch_s) {
    __shared__ float lds[2][2][STG][Dn];   // [buf][K/V][row][d] : 32 KB
    __shared__ float ksred[4][Dn];         // 1 KB

    const int head = blockIdx.x;
    const int chunk = blockIdx.y;
    const int t = threadIdx.x;
    const int w = t >> 6;                  // wave 0..3
    const int l = t & 63;
    const int d0 = (l >> 3) * 8;           // kv row-tile base (K dim)
    const int e0 = (l & 7) * 8;            // kv col-tile base (V dim)
    const int nstg = ch_s / STG;

    const size_t base = ((size_t)head * Sn + (size_t)chunk * ch_s) * Dn;
    const float* kg = K + base + t * 4;    // per-lane global source
    const float* vg = V + base + t * 4;

    float acc[8][8] = {};
    float ks[8] = {};

    auto STAGE = [&](const float* kgp, const float* vgp, int b) {
        float* kl = &lds[b][0][0][0] + w * 256;   // wave-uniform LDS dest base
        float* vl = &lds[b][1][0][0] + w * 256;
        gload16(kgp, kl);
        gload16(kgp + 1024, kl + 1024);
        gload16(vgp, vl);
        gload16(vgp + 1024, vl + 1024);
    };

    STAGE(kg, vg, 0);
    kg += STG * Dn; vg += STG * Dn;
    __syncthreads();   // vmcnt drained before barrier (HIP __syncthreads semantics)

    for (int st = 0; st < nstg; ++st) {
        const int cur = st & 1;
        if (st + 1 < nstg) {
            STAGE(kg, vg, cur ^ 1);
            kg += STG * Dn; vg += STG * Dn;
        }
        const float* kb = &lds[cur][0][w * 8][0];   // this wave's 8 rows
        const float* vb = &lds[cur][1][w * 8][0];
        #pragma unroll
        for (int r = 0; r < 8; ++r) {
            float4 ka = *(const float4*)(kb + r * Dn + d0);
            float4 kc = *(const float4*)(kb + r * Dn + d0 + 4);
            float4 va = *(const float4*)(vb + r * Dn + e0);
            float4 vc = *(const float4*)(vb + r * Dn + e0 + 4);
            float kf[8] = {ka.x, ka.y, ka.z, ka.w, kc.x, kc.y, kc.z, kc.w};
            float vf[8] = {va.x, va.y, va.z, va.w, vc.x, vc.y, vc.z, vc.w};
            #pragma unroll
            for (int i = 0; i < 8; ++i) {
                ks[i] += kf[i];
                #pragma unroll
                for (int j = 0; j < 8; ++j) acc[i][j] += kf[i] * vf[j];
            }
        }
        __syncthreads();   // next stage landed + all waves done reading cur
    }

    // ---- block reduction of the 4 wave partials (both LDS buffers now free) ----
    float* redA = &lds[0][0][0][0];   // 4096 floats
    float* redB = &lds[1][0][0][0];   // 4096 floats
    if (w == 0 || w == 1) {
        float* dst = (w == 0) ? redA : redB;
        #pragma unroll
        for (int i = 0; i < 8; ++i) {
            *(float4*)&dst[(d0 + i) * Dn + e0] =
                make_float4(acc[i][0], acc[i][1], acc[i][2], acc[i][3]);
            *(float4*)&dst[(d0 + i) * Dn + e0 + 4] =
                make_float4(acc[i][4], acc[i][5], acc[i][6], acc[i][7]);
        }
    }
    if ((l & 7) == 0) {
        #pragma unroll
        for (int i = 0; i < 8; ++i) ksred[w][d0 + i] = ks[i];
    }
    __syncthreads();
    if (w == 2 || w == 3) {
        float* dst = (w == 2) ? redA : redB;
        #pragma unroll
        for (int i = 0; i < 8; ++i)
            #pragma unroll
            for (int j = 0; j < 8; ++j) dst[(d0 + i) * Dn + e0 + j] += acc[i][j];
    }
    __syncthreads();

    float* slot = part + ((size_t)chunk * NHEAD + head) * SLOT;
    #pragma unroll
    for (int q = 0; q < 4; ++q) {
        int f = q * 1024 + t * 4;          // coalesced across lanes
        float4 a = *(const float4*)&redA[f];
        float4 b = *(const float4*)&redB[f];
        *(float4*)&slot[f] = make_float4(a.x + b.x, a.y + b.y, a.z + b.z, a.w + b.w);
    }
    if (t < Dn)
        slot[Dn * Dn + t] = ksred[0][t] + ksred[1][t] + ksred[2][t] + ksred[3][t];
}

// ---------------- Reduce chunk-partials -> final slot layout [head][4096 kv + 64 ksum] ----------------
__global__ __launch_bounds__(256) void reduce_partials(const float* __restrict__ part,
                                                       float* __restrict__ slots,
                                                       int nchunks) {
    const int head = blockIdx.x;
    const int idx = blockIdx.y * 256 + threadIdx.x;
    if (idx >= SLOT) return;
    float s = 0.f;
    for (int c = 0; c < nchunks; ++c)
        s += part[((size_t)c * NHEAD + head) * SLOT + idx];
    slots[(size_t)head * SLOT + idx] = s;
}

// ---------------- Pass 2: out = (Q / (Q.ksum + eps)) @ kv ----------------
__global__ __launch_bounds__(256) void pass2(const float* __restrict__ Q,
                                             const float* __restrict__ slots,
                                             float* __restrict__ out) {
    const int head = blockIdx.x;
    const int rc = blockIdx.y;  // 64-row chunk
    const int t = threadIdx.x;
    const int ti = t >> 4, tj = t & 15;
    const int r0 = ti * 4, e0 = tj * 4;   // 4 rows x 4 cols per thread

    __shared__ float kvs[Dn][Dn];
    __shared__ float qT[Dn][68];          // transposed Q tile, padded
    __shared__ float kss[Dn];

    const float* kvh = slots + (size_t)head * SLOT;

    // stage kv (16KB; L2/L3-resident after reduce)
    const float4* kvsrc = (const float4*)kvh;
    float4* kvdst = (float4*)&kvs[0][0];
    #pragma unroll
    for (int kk = 0; kk < 4; ++kk) kvdst[t + 256 * kk] = kvsrc[t + 256 * kk];
    if (t < 16) ((float4*)kss)[t] = ((const float4*)(kvh + Dn * Dn))[t];

    // stage Q tile transposed: qT[d][row]
    const float4* Qsrc = (const float4*)(Q + ((size_t)head * Sn + (size_t)rc * 64) * Dn);
    #pragma unroll
    for (int kk = 0; kk < 4; ++kk) {
        int f = t + 256 * kk;
        int row = f >> 4, d4 = (f & 15) * 4;
        float4 q4 = Qsrc[f];
        qT[d4 + 0][row] = q4.x;
        qT[d4 + 1][row] = q4.y;
        qT[d4 + 2][row] = q4.z;
        qT[d4 + 3][row] = q4.w;
    }
    __syncthreads();

    float acc[4][4] = {};
    float dn[4] = {0.f, 0.f, 0.f, 0.f};
    #pragma unroll 8
    for (int d = 0; d < Dn; ++d) {
        float4 a = *(const float4*)&qT[d][r0];     // q for 4 rows at dim d
        float4 b = *(const float4*)&kvs[d][e0];    // kv row d, 4 cols
        float ksd = kss[d];
        float av[4] = {a.x, a.y, a.z, a.w};
        float bv[4] = {b.x, b.y, b.z, b.w};
        #pragma unroll
        for (int i = 0; i < 4; ++i) {
            dn[i] += av[i] * ksd;
            #pragma unroll
            for (int j = 0; j < 4; ++j) acc[i][j] += av[i] * bv[j];
        }
    }

    float* Oh = out + ((size_t)head * Sn + (size_t)rc * 64) * Dn;
    #pragma unroll
    for (int i = 0; i < 4; ++i) {
        float inv = 1.0f / (dn[i] + FEPS);
        float4 r;
        r.x = acc[i][0] * inv; r.y = acc[i][1] * inv;
        r.z = acc[i][2] * inv; r.w = acc[i][3] * inv;
        *(float4*)&Oh[(size_t)(r0 + i) * Dn + e0] = r;
    }
}

extern "C" void kernel_launch(void* const* d_in, const int* in_sizes, int n_in,
                              void* d_out, int out_size, void* d_ws, size_t ws_size,
                              hipStream_t stream) {
    (void)in_sizes; (void)n_in; (void)out_size;
    const float* Q = (const float*)d_in[0];
    const float* K = (const float*)d_in[1];
    const float* V = (const float*)d_in[2];
    float* out = (float*)d_out;

    float* slots = (float*)d_ws;                         // [64][4160] final kv+ksum

    // pick the largest chunk count whose partial buffer fits in d_ws
    int chunks = 1;
    const int cand[4] = {16, 8, 4, 2};
    for (int ci = 0; ci < 4; ++ci) {
        if ((size_t)(1 + cand[ci]) * NHEAD * SLOT * sizeof(float) <= ws_size) {
            chunks = cand[ci];
            break;
        }
    }

    if (chunks > 1) {
        float* part = slots + (size_t)NHEAD * SLOT;      // [chunks][64][4160]
        hipLaunchKernelGGL(pass1, dim3(NHEAD, chunks), dim3(256), 0, stream,
                           K, V, part, Sn / chunks);
        hipLaunchKernelGGL(reduce_partials, dim3(NHEAD, (SLOT + 255) / 256), dim3(256), 0, stream,
                           part, slots, chunks);
    } else {
        // one block per head writes the final slot directly (no reduce needed)
        hipLaunchKernelGGL(pass1, dim3(NHEAD, 1), dim3(256), 0, stream,
                           K, V, slots, Sn);
    }
    hipLaunchKernelGGL(pass2, dim3(NHEAD, Sn / 64), dim3(256), 0, stream,
                       Q, slots, out);
}